// Round 5
// baseline (53.452 us; speedup 1.0000x reference)
//
#include <hip/hip_runtime.h>

// SineGen — accurate-phase formulation, round 5: occupancy + MLP restructure.
//
// phase(b,t,u,h) = (S + (u+1)*f0) * kh + ri,  kh=(h+1)/44100,
//   S(b,t) = sum_{t'<t} 256*f0(b,t')   (16 f64 scans of 1000)
// Per frame (f64, setup lanes):  M = frac(S*kh + ri),  D = frac(f0*kh)
// Per element (f32):             fr = fract(fmaf(u+1, D, M));  s = v_sin(fr)
// Branchless: out = An*noise + As*sin, (As,An) = voiced?(0.1,0.003):(0,0.1/3)
//
// Emit: 512 thr (8 waves), 8 frames/block, 9 float4/thread, all loads issued
// before compute (144 B in flight/thread), {D,M,As,An} as one LDS float4 ->
// single ds_read_b128 per element. __launch_bounds__(512,6) for >=24 waves/CU.

constexpr int B     = 16;
constexpr int T     = 1000;
constexpr int UPP   = 256;
constexpr int H     = 9;           // HARMONIC_NUM + 1
constexpr int FPB   = 8;           // frames per block (8 | 1000 per batch row)
constexpr int FRAME = UPP * H;     // 2304 floats per frame
constexpr int NF4   = FPB * FRAME / 4;  // 4608 float4 per block
constexpr int THR   = 512;
constexpr int K     = NF4 / THR;   // 9 float4 per thread

typedef float f32x4 __attribute__((ext_vector_type(4)));

__global__ __launch_bounds__(1024)
void sinegen_scan_kernel(const float* __restrict__ f0,
                         double* __restrict__ S /* [B][T] exclusive prefix */) {
    const int b = blockIdx.x;
    const int t = threadIdx.x;
    __shared__ double lds[1024];

    double d = 0.0;
    if (t < T) d = 256.0 * (double)f0[b * T + t];
    lds[t] = d;
    __syncthreads();

    for (int off = 1; off < 1024; off <<= 1) {
        double add = (t >= off) ? lds[t - off] : 0.0;
        __syncthreads();
        lds[t] += add;
        __syncthreads();
    }
    if (t < T) S[b * T + t] = (t > 0) ? lds[t - 1] : 0.0;
}

__global__ __launch_bounds__(THR, 6)
void sinegen_emit_kernel(const float* __restrict__ f0,
                         const float* __restrict__ rand_ini,
                         const float* __restrict__ noise,
                         const double* __restrict__ S,
                         float* __restrict__ out) {
    const int blk = blockIdx.x;          // 0 .. B*T/FPB-1 (frames never cross b)
    const int tid = threadIdx.x;         // 0..511

    __shared__ f32x4 MD[FPB * H];        // {D, M, As, An} per (frame, harmonic)

    if (tid < FPB * H) {
        const int q  = tid / H;
        const int h  = tid - q * H;
        const int fg = blk * FPB + q;    // global frame index = b*T + t
        const int b  = fg / T;
        const float  f0v = f0[fg];
        const double kh  = (double)(h + 1) * (1.0 / 44100.0);
        const double md  = S[fg] * kh + (double)rand_ini[b * H + h];
        const double dd  = (double)f0v * kh;
        const bool   v   = (f0v > 0.0f);
        f32x4 w;
        w.x = (float)(dd - floor(dd));                  // D
        w.y = (float)(md - floor(md));                  // M
        w.z = v ? 0.1f   : 0.0f;                        // As
        w.w = v ? 0.003f : (float)(0.1 / 3.0);          // An
        MD[tid] = w;
    }
    __syncthreads();

    const float* nbase = noise + (size_t)blk * (FPB * FRAME);
    float*       obase = out   + (size_t)blk * (FPB * FRAME);

    // Issue all 9 float4 loads first — 144 B in flight per thread, coalesced.
    f32x4 nz[K];
    #pragma unroll
    for (int k = 0; k < K; ++k)
        nz[k] = *(const f32x4*)(nbase + (k * THR + tid) * 4);

    #pragma unroll
    for (int k = 0; k < K; ++k) {
        const int idx = k * THR + tid;   // float4 index within block, 0..4607
        const int q   = idx / (FRAME / 4);          // frame-in-block, 0..7
        const int r   = idx - q * (FRAME / 4);      // float4-in-frame, 0..575
        f32x4 o;
        #pragma unroll
        for (int j = 0; j < 4; ++j) {
            const int   e  = r * 4 + j;             // 0..2303
            const int   u  = e / 9;                 // const-div -> magic mul
            const int   h  = e - u * 9;
            const f32x4 md = MD[q * H + h];         // one ds_read_b128
            const float p  = fmaf((float)(u + 1), md.x, md.y);
            const float fr = __builtin_amdgcn_fractf(p);   // v_fract_f32
            float s;
            asm("v_sin_f32 %0, %1" : "=v"(s) : "v"(fr));   // sin(2*pi*fr)
            o[j] = fmaf(md.w, nz[k][j], md.z * s);
        }
        __builtin_nontemporal_store(o, (f32x4*)(obase + idx * 4));
    }
}

extern "C" void kernel_launch(void* const* d_in, const int* in_sizes, int n_in,
                              void* d_out, int out_size, void* d_ws, size_t ws_size,
                              hipStream_t stream) {
    const float* f0       = (const float*)d_in[0];   // [B][T]
    const float* rand_ini = (const float*)d_in[1];   // [B][H]
    const float* noise    = (const float*)d_in[2];   // [B][T*UPP][H]
    float*       out      = (float*)d_out;           // [B][T*UPP][H]
    double*      Sws      = (double*)d_ws;           // [B][T] = 128 KB

    sinegen_scan_kernel<<<B, 1024, 0, stream>>>(f0, Sws);
    sinegen_emit_kernel<<<(B * T) / FPB, THR, 0, stream>>>(f0, rand_ini, noise,
                                                           Sws, out);
}

// Round 6
// 49.757 us; speedup vs baseline: 1.0742x; 1.0742x over previous
//
#include <hip/hip_runtime.h>

// SineGen — round 6: single fused kernel (scan folded into emit).
//
// phase(b,t,u,h) = (S + (u+1)*f0) * kh + ri,  kh=(h+1)/44100,
//   S(b,t) = 256 * sum_{t'<t} f0(b,t')
// Each block (8 frames, never crossing a batch row) recomputes S(b,t0) itself:
// block-parallel f64 reduction over f0[b,0..t0) (L2-resident, order-free at
// f64 precision), then <=7 f64 adds for the in-block frame prefix.
// Per frame (f64, setup lanes):  M = frac(S*kh + ri),  D = frac(f0*kh)
// Per element (f32):             fr = fract(fmaf(u+1, D, M));  s = v_sin(fr)
// Branchless: out = An*noise + As*sin, (As,An) = voiced?(0.1,0.003):(0,0.1/3)
//
// Emit is at the request-path roofline: 295 MB compulsory (noise read + out
// write) at the ~6.3 TB/s measured mixed-stream ceiling => ~46 us.

constexpr int B     = 16;
constexpr int T     = 1000;
constexpr int UPP   = 256;
constexpr int H     = 9;           // HARMONIC_NUM + 1
constexpr int FPB   = 8;           // frames per block (125 blocks per row)
constexpr int BPR   = T / FPB;     // 125
constexpr int FRAME = UPP * H;     // 2304 floats per frame
constexpr int NF4   = FPB * FRAME / 4;  // 4608 float4 per block
constexpr int THR   = 512;
constexpr int K     = NF4 / THR;   // 9 float4 per thread

typedef float f32x4 __attribute__((ext_vector_type(4)));

__global__ __launch_bounds__(THR, 6)
void sinegen_fused_kernel(const float* __restrict__ f0,
                          const float* __restrict__ rand_ini,
                          const float* __restrict__ noise,
                          float* __restrict__ out) {
    const int blk = blockIdx.x;          // 0..1999
    const int tid = threadIdx.x;         // 0..511
    const int b   = blk / BPR;
    const int t0  = (blk - b * BPR) * FPB;

    __shared__ double wsum[THR / 64];    // per-wave partials
    __shared__ double f0d[FPB];          // 256*f0 for the block's 8 frames (f64)
    __shared__ double Sblk;              // S(b, t0)
    __shared__ f32x4  MD[FPB * H];       // {D, M, As, An} per (frame, harmonic)

    const float* f0row = f0 + b * T;

    // ---- Block-parallel f64 reduction: S(b,t0) = 256 * sum f0row[0..t0) ----
    double part = 0.0;
    for (int t = tid; t < t0; t += THR) part += (double)f0row[t];
    #pragma unroll
    for (int off = 32; off > 0; off >>= 1) part += __shfl_down(part, off, 64);
    if ((tid & 63) == 0) wsum[tid >> 6] = part;
    if (tid < FPB) f0d[tid] = 256.0 * (double)f0row[t0 + tid];  // pow2: exact
    __syncthreads();
    if (tid == 0) {
        double s = 0.0;
        #pragma unroll
        for (int w = 0; w < THR / 64; ++w) s += wsum[w];
        Sblk = 256.0 * s;                                       // pow2: exact
    }
    __syncthreads();

    // ---- Per-(frame, harmonic) setup in f64 ----
    if (tid < FPB * H) {
        const int q  = tid / H;
        const int h  = tid - q * H;
        double Sq = Sblk;
        for (int i = 0; i < q; ++i) Sq += f0d[i];   // <=7 adds, in-block prefix
        const float  f0v = f0row[t0 + q];
        const double kh  = (double)(h + 1) * (1.0 / 44100.0);
        const double md  = Sq * kh + (double)rand_ini[b * H + h];
        const double dd  = (double)f0v * kh;
        const bool   v   = (f0v > 0.0f);
        f32x4 w;
        w.x = (float)(dd - floor(dd));                  // D
        w.y = (float)(md - floor(md));                  // M
        w.z = v ? 0.1f   : 0.0f;                        // As
        w.w = v ? 0.003f : (float)(0.1 / 3.0);          // An
        MD[tid] = w;
    }
    __syncthreads();

    const float* nbase = noise + (size_t)blk * (FPB * FRAME);
    float*       obase = out   + (size_t)blk * (FPB * FRAME);

    // Issue all 9 float4 loads first — 144 B in flight per thread, coalesced.
    f32x4 nz[K];
    #pragma unroll
    for (int k = 0; k < K; ++k)
        nz[k] = *(const f32x4*)(nbase + (k * THR + tid) * 4);

    #pragma unroll
    for (int k = 0; k < K; ++k) {
        const int idx = k * THR + tid;              // float4 index, 0..4607
        const int q   = idx / (FRAME / 4);          // frame-in-block, 0..7
        const int r   = idx - q * (FRAME / 4);      // float4-in-frame, 0..575
        f32x4 o;
        #pragma unroll
        for (int j = 0; j < 4; ++j) {
            const int   e  = r * 4 + j;             // 0..2303
            const int   u  = e / 9;                 // const-div -> magic mul
            const int   h  = e - u * 9;
            const f32x4 md = MD[q * H + h];         // one ds_read_b128
            const float p  = fmaf((float)(u + 1), md.x, md.y);
            const float fr = __builtin_amdgcn_fractf(p);   // v_fract_f32
            float s;
            asm("v_sin_f32 %0, %1" : "=v"(s) : "v"(fr));   // sin(2*pi*fr)
            o[j] = fmaf(md.w, nz[k][j], md.z * s);
        }
        __builtin_nontemporal_store(o, (f32x4*)(obase + idx * 4));
    }
}

extern "C" void kernel_launch(void* const* d_in, const int* in_sizes, int n_in,
                              void* d_out, int out_size, void* d_ws, size_t ws_size,
                              hipStream_t stream) {
    const float* f0       = (const float*)d_in[0];   // [B][T]
    const float* rand_ini = (const float*)d_in[1];   // [B][H]
    const float* noise    = (const float*)d_in[2];   // [B][T*UPP][H]
    float*       out      = (float*)d_out;           // [B][T*UPP][H]

    sinegen_fused_kernel<<<(B * T) / FPB, THR, 0, stream>>>(f0, rand_ini,
                                                            noise, out);
}